// Round 1
// 233.338 us; speedup vs baseline: 1.0453x; 1.0453x over previous
//
#include <hip/hip_runtime.h>
#include <hip/hip_bf16.h>

#define NFP    10000
#define DIM    70
#define GPAD   72      // row stride in u16 for G and gTs (144 B = 16B-aligned rows)
#define NATOMS 64
#define PGROWS 16      // vocab rows per precompute block

typedef short  short8  __attribute__((ext_vector_type(8)));
typedef float  floatx4 __attribute__((ext_vector_type(4)));

__device__ inline unsigned short f2bf(float f) {
  union { float f; unsigned u; } x; x.f = f;
  unsigned r = x.u + 0x7fffu + ((x.u >> 16) & 1u);
  return (unsigned short)(r >> 16);
}

__device__ inline ushort2 pk2bf(float a, float b) {
  __hip_bfloat162 h = __float22bfloat162_rn(make_float2(a, b));
  union { __hip_bfloat162 h; ushort2 u; } c; c.h = h; return c.u;
}

// G[v][72] (bf16, cols 70,71 = 0) = relu(emb[v] @ w1 + b1) @ w2
__global__ __launch_bounds__(256) void precompute_G(
    const float* __restrict__ emb, const float* __restrict__ w1,
    const float* __restrict__ b1,  const float* __restrict__ w2,
    unsigned short* __restrict__ G) {
  __shared__ float w1s[DIM * GPAD];
  __shared__ float w2s[DIM * GPAD];
  __shared__ float b1s[GPAD];
  __shared__ float embs[PGROWS * GPAD];
  __shared__ float e1s[PGROWS * GPAD];
  const int t = threadIdx.x;

  for (int i = t; i < DIM * GPAD; i += 256) {
    int r = i / GPAD, c = i % GPAD;
    float v1 = 0.f, v2 = 0.f;
    if (c < DIM) { v1 = w1[r * DIM + c]; v2 = w2[r * DIM + c]; }
    w1s[i] = v1; w2s[i] = v2;
  }
  if (t < GPAD) b1s[t] = (t < DIM) ? b1[t] : 0.f;
  const int row0 = blockIdx.x * PGROWS;
  for (int i = t; i < PGROWS * GPAD; i += 256) {
    int r = i / GPAD, c = i % GPAD;
    int vr = row0 + r;
    embs[i] = (vr < NFP && c < DIM) ? emb[vr * DIM + c] : 0.f;
  }
  __syncthreads();

  for (int task = t; task < PGROWS * 18; task += 256) {
    int r = task / 18, c4 = (task % 18) * 4;
    float4 acc = *(const float4*)&b1s[c4];
    for (int k = 0; k < DIM; k++) {
      float e = embs[r * GPAD + k];
      float4 w = *(const float4*)&w1s[k * GPAD + c4];
      acc.x = fmaf(e, w.x, acc.x); acc.y = fmaf(e, w.y, acc.y);
      acc.z = fmaf(e, w.z, acc.z); acc.w = fmaf(e, w.w, acc.w);
    }
    acc.x = fmaxf(acc.x, 0.f); acc.y = fmaxf(acc.y, 0.f);
    acc.z = fmaxf(acc.z, 0.f); acc.w = fmaxf(acc.w, 0.f);
    *(float4*)&e1s[r * GPAD + c4] = acc;
  }
  __syncthreads();

  for (int task = t; task < PGROWS * 18; task += 256) {
    int r = task / 18, c4 = (task % 18) * 4;
    int vr = row0 + r;
    if (vr >= NFP) continue;
    float ax = 0.f, ay = 0.f, az = 0.f, aw = 0.f;
    for (int k = 0; k < DIM; k++) {
      float e = e1s[r * GPAD + k];
      float4 w = *(const float4*)&w2s[k * GPAD + c4];
      ax = fmaf(e, w.x, ax); ay = fmaf(e, w.y, ay);
      az = fmaf(e, w.z, az); aw = fmaf(e, w.w, aw);
    }
    unsigned short* gp = G + vr * GPAD + c4;
    gp[0] = f2bf(ax); gp[1] = f2bf(ay); gp[2] = f2bf(az); gp[3] = f2bf(aw);
  }
}

// One block per molecule: y = colsum(adj) @ relu(adj @ G[atoms] + b2);
// out = [y, sel] @ wp + bp, all fused.
// v2: all global loads issued before any LDS traffic; 2 barriers (was 4);
//     satoms/b2p/yv LDS buffers removed; one-wave butterfly tail;
//     launch_bounds(256,7): VGPR<=72 so 7 blocks/CU (LDS=22.5 KB -> 7).
__global__ __launch_bounds__(256, 7) void mol_fused(
    const int* __restrict__ atoms, const float* __restrict__ adj,
    const float* __restrict__ sel, const float* __restrict__ b2,
    const float* __restrict__ wp,  const float* __restrict__ bp,
    const unsigned short* __restrict__ G, float* __restrict__ out) {
  __shared__ unsigned short adjs[64 * GPAD];   // adj bf16, pad 72      (9216 B)
  __shared__ unsigned short gTs[80 * GPAD];    // gT[d][m] bf16         (11520 B)
  // rows 70,71 of gTs are true zeros (G cols 70,71 = 0); rows 72..79 are
  // stale garbage -- their MFMA output columns (d=72..79) are never read.
  __shared__ float cwave[4 * 64];              // per-wave colsum partials
  __shared__ float yacc[4 * 80];               // per-wave y partials

  const int b = blockIdx.x;
  const int t = threadIdx.x;
  const int w = t >> 6, lane = t & 63;
  const int q = lane >> 4, li = lane & 15;
  const int R = w * 16;
  const int m = lane;                          // atom index this thread gathers

  // ---- phase 0: issue ALL global loads up front (overlap HBM + L2 latency) ----
  const int myAtom = atoms[b * 64 + m];        // 256B broadcast, L2-hit
  const float* ap = adj + (size_t)b * 4096;
  const int mc = (t & 15) * 4;
  const int a  = t >> 4;                       // 0..15 block-wide
  float4 v0 = *(const float4*)(ap + (a     ) * 64 + mc);
  float4 v1 = *(const float4*)(ap + (a + 16) * 64 + mc);
  float4 v2 = *(const float4*)(ap + (a + 32) * 64 + mc);
  float4 v3 = *(const float4*)(ap + (a + 48) * 64 + mc);
  const uint4* Gv = (const uint4*)G;           // 9 uint4 per 72-u16 row
  uint4 g0 = Gv[(unsigned)myAtom * 9 + w];
  uint4 g1 = Gv[(unsigned)myAtom * 9 + w + 4];
  uint4 g2;
  if (w == 0) g2 = Gv[(unsigned)myAtom * 9 + 8];

  // ---- adj: colsum + bf16 convert + stage to LDS (conflict-free phasing) ----
  {
    float4 cs;
    cs.x = (v0.x + v1.x) + (v2.x + v3.x);
    cs.y = (v0.y + v1.y) + (v2.y + v3.y);
    cs.z = (v0.z + v1.z) + (v2.z + v3.z);
    cs.w = (v0.w + v1.w) + (v2.w + v3.w);
#pragma unroll
    for (int s = 16; s <= 32; s <<= 1) {
      cs.x += __shfl_xor(cs.x, s); cs.y += __shfl_xor(cs.y, s);
      cs.z += __shfl_xor(cs.z, s); cs.w += __shfl_xor(cs.w, s);
    }
    if (((t >> 4) & 3) == 0) *(float4*)&cwave[w * 64 + mc] = cs;

    float4 vv[4] = {v0, v1, v2, v3};
#pragma unroll
    for (int it = 0; it < 4; it++) {
      int n = a + 16 * it;
      ushort2 lo = pk2bf(vv[it].x, vv[it].y);
      ushort2 hi = pk2bf(vv[it].z, vv[it].w);
      ushort4 u; u.x = lo.x; u.y = lo.y; u.z = hi.x; u.w = hi.y;
      *(ushort4*)&adjs[n * GPAD + mc] = u;
    }
  }

  // ---- G gather -> transpose into gT[d][m] (consecutive-m writes, 2-way free) ----
  {
    unsigned short* gp0 = &gTs[(w * 8) * GPAD + m];
    gp0[0 * GPAD] = (unsigned short)(g0.x & 0xffff);
    gp0[1 * GPAD] = (unsigned short)(g0.x >> 16);
    gp0[2 * GPAD] = (unsigned short)(g0.y & 0xffff);
    gp0[3 * GPAD] = (unsigned short)(g0.y >> 16);
    gp0[4 * GPAD] = (unsigned short)(g0.z & 0xffff);
    gp0[5 * GPAD] = (unsigned short)(g0.z >> 16);
    gp0[6 * GPAD] = (unsigned short)(g0.w & 0xffff);
    gp0[7 * GPAD] = (unsigned short)(g0.w >> 16);
    unsigned short* gp1 = &gTs[((w + 4) * 8) * GPAD + m];
    gp1[0 * GPAD] = (unsigned short)(g1.x & 0xffff);
    gp1[1 * GPAD] = (unsigned short)(g1.x >> 16);
    gp1[2 * GPAD] = (unsigned short)(g1.y & 0xffff);
    gp1[3 * GPAD] = (unsigned short)(g1.y >> 16);
    gp1[4 * GPAD] = (unsigned short)(g1.z & 0xffff);
    gp1[5 * GPAD] = (unsigned short)(g1.z >> 16);
    gp1[6 * GPAD] = (unsigned short)(g1.w & 0xffff);
    gp1[7 * GPAD] = (unsigned short)(g1.w >> 16);
    if (w == 0) {
      unsigned short* gp2 = &gTs[64 * GPAD + m];
      gp2[0 * GPAD] = (unsigned short)(g2.x & 0xffff);
      gp2[1 * GPAD] = (unsigned short)(g2.x >> 16);
      gp2[2 * GPAD] = (unsigned short)(g2.y & 0xffff);
      gp2[3 * GPAD] = (unsigned short)(g2.y >> 16);
      gp2[4 * GPAD] = (unsigned short)(g2.z & 0xffff);
      gp2[5 * GPAD] = (unsigned short)(g2.z >> 16);
      gp2[6 * GPAD] = (unsigned short)(g2.w & 0xffff);
      gp2[7 * GPAD] = (unsigned short)(g2.w >> 16);
    }
  }
  __syncthreads();   // barrier 1 of 2

  // ---- per-lane colsum weights for its 4 output rows (exact fp32) ----
  float cr[4];
#pragma unroll
  for (int r = 0; r < 4; r++) {
    int mm = R + q * 4 + r;
    cr[r] = cwave[mm] + cwave[64 + mm] + cwave[128 + mm] + cwave[192 + mm];
  }
  // b2 direct from global (L1-hot across blocks); issued before MFMA to hide
  float bbv[5];
#pragma unroll
  for (int nt = 0; nt < 5; nt++) {
    int d = nt * 16 + li;
    bbv[nt] = (d < DIM) ? b2[d] : 0.f;
  }

  // ---- MFMA: h2pre[64][80] = adj @ g; wave w owns rows 16w..16w+15 ----
  short8 a0 = *(const short8*)&adjs[(R + li) * GPAD + q * 8];
  short8 a1 = *(const short8*)&adjs[(R + li) * GPAD + 32 + q * 8];
  floatx4 acc[5];
#pragma unroll
  for (int nt = 0; nt < 5; nt++) {
    floatx4 z = {0.f, 0.f, 0.f, 0.f};
    short8 b0 = *(const short8*)&gTs[(nt * 16 + li) * GPAD + q * 8];
    short8 b1 = *(const short8*)&gTs[(nt * 16 + li) * GPAD + 32 + q * 8];
    z = __builtin_amdgcn_mfma_f32_16x16x32_bf16(a0, b0, z, 0, 0, 0);
    z = __builtin_amdgcn_mfma_f32_16x16x32_bf16(a1, b1, z, 0, 0, 0);
    acc[nt] = z;
  }

  // ---- epilogue: y[d] = sum_m cvec[m] * relu(h2pre[m][d] + b2[d]) ----
#pragma unroll
  for (int nt = 0; nt < 5; nt++) {
    float bb = bbv[nt];
    float p = 0.f;
#pragma unroll
    for (int r = 0; r < 4; r++)
      p = fmaf(cr[r], fmaxf(acc[nt][r] + bb, 0.f), p);
    p += __shfl_xor(p, 16);
    p += __shfl_xor(p, 32);
    if (q == 0) yacc[w * 80 + nt * 16 + li] = p;
  }
  __syncthreads();   // barrier 2 of 2

  // ---- tail: wave 0 only. lane covers d=lane and d2=lane+64 (<77). ----
  if (w == 0) {
    float val = yacc[lane] + yacc[80 + lane] + yacc[160 + lane] + yacc[240 + lane];
    int d2 = 64 + lane;
    float val2 = 0.f;
    if (lane < 6)        val2 = yacc[d2] + yacc[80 + d2] + yacc[160 + d2] + yacc[240 + d2];
    else if (lane < 13)  val2 = sel[(size_t)b * 7 + (d2 - DIM)];
    float pc[11];
#pragma unroll
    for (int c = 0; c < 11; c++) pc[c] = val * wp[lane * 11 + c];
    if (lane < 13) {
#pragma unroll
      for (int c = 0; c < 11; c++) pc[c] = fmaf(val2, wp[d2 * 11 + c], pc[c]);
    }
#pragma unroll
    for (int s = 1; s <= 32; s <<= 1) {
#pragma unroll
      for (int c = 0; c < 11; c++) pc[c] += __shfl_xor(pc[c], s);
    }
    if (lane < 11) out[(size_t)b * 11 + lane] = pc[lane] + bp[lane];
  }
}

extern "C" void kernel_launch(void* const* d_in, const int* in_sizes, int n_in,
                              void* d_out, int out_size, void* d_ws, size_t ws_size,
                              hipStream_t stream) {
  const int*   atoms = (const int*)d_in[0];
  const float* adj   = (const float*)d_in[1];
  const float* sel   = (const float*)d_in[2];
  const float* emb   = (const float*)d_in[3];
  const float* w1    = (const float*)d_in[4];
  const float* b1    = (const float*)d_in[5];
  const float* w2    = (const float*)d_in[6];
  const float* b2    = (const float*)d_in[7];
  const float* wp    = (const float*)d_in[8];
  const float* bp    = (const float*)d_in[9];

  const int B = in_sizes[0] / NATOMS;          // 8192
  unsigned short* G = (unsigned short*)d_ws;   // 10000*72 bf16 = 1.44 MB

  precompute_G<<<(NFP + PGROWS - 1) / PGROWS, 256, 0, stream>>>(emb, w1, b1, w2, G);
  mol_fused<<<B, 256, 0, stream>>>(atoms, adj, sel, b2, wp, bp, G, (float*)d_out);
}

// Round 4
// 233.087 us; speedup vs baseline: 1.0465x; 1.0011x over previous
//
#include <hip/hip_runtime.h>
#include <hip/hip_bf16.h>

#define NFP    10000
#define DIM    70
#define GPAD   72      // row stride in u16 for G, adjs, gTs (144 B rows)
#define NATOMS 64
#define PGROWS 16      // vocab rows per precompute block

typedef short  short8  __attribute__((ext_vector_type(8)));
typedef float  floatx4 __attribute__((ext_vector_type(4)));

__device__ inline unsigned short f2bf(float f) {
  union { float f; unsigned u; } x; x.f = f;
  unsigned r = x.u + 0x7fffu + ((x.u >> 16) & 1u);
  return (unsigned short)(r >> 16);
}

__device__ inline ushort2 pk2bf(float a, float b) {
  __hip_bfloat162 h = __float22bfloat162_rn(make_float2(a, b));
  union { __hip_bfloat162 h; ushort2 u; } c; c.h = h; return c.u;
}

// G[v][72] (bf16, cols 70,71 = 0) = relu(emb[v] @ w1 + b1) @ w2   (unchanged)
__global__ __launch_bounds__(256) void precompute_G(
    const float* __restrict__ emb, const float* __restrict__ w1,
    const float* __restrict__ b1,  const float* __restrict__ w2,
    unsigned short* __restrict__ G) {
  __shared__ float w1s[DIM * GPAD];
  __shared__ float w2s[DIM * GPAD];
  __shared__ float b1s[GPAD];
  __shared__ float embs[PGROWS * GPAD];
  __shared__ float e1s[PGROWS * GPAD];
  const int t = threadIdx.x;

  for (int i = t; i < DIM * GPAD; i += 256) {
    int r = i / GPAD, c = i % GPAD;
    float v1 = 0.f, v2 = 0.f;
    if (c < DIM) { v1 = w1[r * DIM + c]; v2 = w2[r * DIM + c]; }
    w1s[i] = v1; w2s[i] = v2;
  }
  if (t < GPAD) b1s[t] = (t < DIM) ? b1[t] : 0.f;
  const int row0 = blockIdx.x * PGROWS;
  for (int i = t; i < PGROWS * GPAD; i += 256) {
    int r = i / GPAD, c = i % GPAD;
    int vr = row0 + r;
    embs[i] = (vr < NFP && c < DIM) ? emb[vr * DIM + c] : 0.f;
  }
  __syncthreads();

  for (int task = t; task < PGROWS * 18; task += 256) {
    int r = task / 18, c4 = (task % 18) * 4;
    float4 acc = *(const float4*)&b1s[c4];
    for (int k = 0; k < DIM; k++) {
      float e = embs[r * GPAD + k];
      float4 w = *(const float4*)&w1s[k * GPAD + c4];
      acc.x = fmaf(e, w.x, acc.x); acc.y = fmaf(e, w.y, acc.y);
      acc.z = fmaf(e, w.z, acc.z); acc.w = fmaf(e, w.w, acc.w);
    }
    acc.x = fmaxf(acc.x, 0.f); acc.y = fmaxf(acc.y, 0.f);
    acc.z = fmaxf(acc.z, 0.f); acc.w = fmaxf(acc.w, 0.f);
    *(float4*)&e1s[r * GPAD + c4] = acc;
  }
  __syncthreads();

  for (int task = t; task < PGROWS * 18; task += 256) {
    int r = task / 18, c4 = (task % 18) * 4;
    int vr = row0 + r;
    if (vr >= NFP) continue;
    float ax = 0.f, ay = 0.f, az = 0.f, aw = 0.f;
    for (int k = 0; k < DIM; k++) {
      float e = e1s[r * GPAD + k];
      float4 w = *(const float4*)&w2s[k * GPAD + c4];
      ax = fmaf(e, w.x, ax); ay = fmaf(e, w.y, ay);
      az = fmaf(e, w.z, az); aw = fmaf(e, w.w, aw);
    }
    unsigned short* gp = G + vr * GPAD + c4;
    gp[0] = f2bf(ax); gp[1] = f2bf(ay); gp[2] = f2bf(az); gp[3] = f2bf(aw);
  }
}

// v4: structurally the proven v2 kernel (no inline asm), plus the safe subset
//     of v3's DS cuts: vector cr reads (4x ds_read_b128), cheap wave-0 tail
//     (yv aliases dead cwave; 20 fma + 2 shuffles, was 66 shuffles), gTs
//     rows 72..79 left unwritten (their MFMA output columns feed only
//     yacc[d>=72], which the tail never reads), launch_bounds(256,6) so the
//     prefetch schedule survives regalloc (v2's (256,7) capped VGPR at 72).
__global__ __launch_bounds__(256, 6) void mol_fused(
    const int* __restrict__ atoms, const float* __restrict__ adj,
    const float* __restrict__ sel, const float* __restrict__ b2,
    const float* __restrict__ wp,  const float* __restrict__ bp,
    const unsigned short* __restrict__ G, float* __restrict__ out) {
  __shared__ unsigned short adjs[64 * GPAD];   // adj bf16 (9216 B)
  __shared__ unsigned short gTs[80 * GPAD];    // gT[d][m] bf16 (11520 B); rows 72..79 garbage, quarantined
  __shared__ float cwave[4 * 64];              // colsum partials; reused as yv[80] in tail
  __shared__ float yacc[4 * 80];               // per-wave y partials
  // total 23040 B -> 7 blocks/CU by LDS

  const int b = blockIdx.x;
  const int t = threadIdx.x;
  const int w = t >> 6, lane = t & 63;
  const int q = lane >> 4, li = lane & 15;
  const int R = w * 16;
  const int m = lane;                          // atom index this thread gathers

  // ---- phase 0: issue ALL global loads up front (overlap HBM + L2 latency) ----
  const float* ap = adj + (size_t)b * 4096;
  const int mc = (t & 15) * 4;
  const int a  = t >> 4;
  float4 v0 = *(const float4*)(ap + (a     ) * 64 + mc);
  float4 v1 = *(const float4*)(ap + (a + 16) * 64 + mc);
  float4 v2 = *(const float4*)(ap + (a + 32) * 64 + mc);
  float4 v3 = *(const float4*)(ap + (a + 48) * 64 + mc);
  const int myAtom = atoms[b * 64 + m];        // L2-hit broadcast
  const uint4* Gv = (const uint4*)G;           // 9 uint4 per 72-u16 row
  uint4 g0 = Gv[(unsigned)myAtom * 9 + w];
  uint4 g1 = Gv[(unsigned)myAtom * 9 + w + 4];
  uint4 g2; g2.x = g2.y = g2.z = g2.w = 0u;
  if (w == 0) g2 = Gv[(unsigned)myAtom * 9 + 8];

  // ---- adj: colsum + bf16 convert + stage to LDS ----
  {
    float4 cs;
    cs.x = (v0.x + v1.x) + (v2.x + v3.x);
    cs.y = (v0.y + v1.y) + (v2.y + v3.y);
    cs.z = (v0.z + v1.z) + (v2.z + v3.z);
    cs.w = (v0.w + v1.w) + (v2.w + v3.w);
#pragma unroll
    for (int s = 16; s <= 32; s <<= 1) {
      cs.x += __shfl_xor(cs.x, s); cs.y += __shfl_xor(cs.y, s);
      cs.z += __shfl_xor(cs.z, s); cs.w += __shfl_xor(cs.w, s);
    }
    if (((t >> 4) & 3) == 0) *(float4*)&cwave[w * 64 + mc] = cs;

    float4 vv[4] = {v0, v1, v2, v3};
#pragma unroll
    for (int it = 0; it < 4; it++) {
      int n = a + 16 * it;
      ushort2 lo = pk2bf(vv[it].x, vv[it].y);
      ushort2 hi = pk2bf(vv[it].z, vv[it].w);
      ushort4 u; u.x = lo.x; u.y = lo.y; u.z = hi.x; u.w = hi.y;
      *(ushort4*)&adjs[n * GPAD + mc] = u;
    }
  }

  // ---- G gather -> transpose into gT[d][m] (consecutive-m writes, 2-way free) ----
  {
    unsigned short* gp0 = &gTs[(w * 8) * GPAD + m];
    gp0[0 * GPAD] = (unsigned short)(g0.x & 0xffff);
    gp0[1 * GPAD] = (unsigned short)(g0.x >> 16);
    gp0[2 * GPAD] = (unsigned short)(g0.y & 0xffff);
    gp0[3 * GPAD] = (unsigned short)(g0.y >> 16);
    gp0[4 * GPAD] = (unsigned short)(g0.z & 0xffff);
    gp0[5 * GPAD] = (unsigned short)(g0.z >> 16);
    gp0[6 * GPAD] = (unsigned short)(g0.w & 0xffff);
    gp0[7 * GPAD] = (unsigned short)(g0.w >> 16);
    unsigned short* gp1 = &gTs[((w + 4) * 8) * GPAD + m];
    gp1[0 * GPAD] = (unsigned short)(g1.x & 0xffff);
    gp1[1 * GPAD] = (unsigned short)(g1.x >> 16);
    gp1[2 * GPAD] = (unsigned short)(g1.y & 0xffff);
    gp1[3 * GPAD] = (unsigned short)(g1.y >> 16);
    gp1[4 * GPAD] = (unsigned short)(g1.z & 0xffff);
    gp1[5 * GPAD] = (unsigned short)(g1.z >> 16);
    gp1[6 * GPAD] = (unsigned short)(g1.w & 0xffff);
    gp1[7 * GPAD] = (unsigned short)(g1.w >> 16);
    if (w == 0) {
      unsigned short* gp2 = &gTs[64 * GPAD + m];
      gp2[0 * GPAD] = (unsigned short)(g2.x & 0xffff);
      gp2[1 * GPAD] = (unsigned short)(g2.x >> 16);
      gp2[2 * GPAD] = (unsigned short)(g2.y & 0xffff);
      gp2[3 * GPAD] = (unsigned short)(g2.y >> 16);
      gp2[4 * GPAD] = (unsigned short)(g2.z & 0xffff);
      gp2[5 * GPAD] = (unsigned short)(g2.z >> 16);
      gp2[6 * GPAD] = (unsigned short)(g2.w & 0xffff);
      gp2[7 * GPAD] = (unsigned short)(g2.w >> 16);
    }
    // rows 72..79 deliberately unwritten (outputs quarantined)
  }
  __syncthreads();   // barrier 1 of 2

  // ---- per-lane colsum weights, vector reads (broadcast across li) ----
  float cr[4];
  {
    float4 c0 = *(const float4*)&cwave[      R + q * 4];
    float4 c1 = *(const float4*)&cwave[ 64 + R + q * 4];
    float4 c2 = *(const float4*)&cwave[128 + R + q * 4];
    float4 c3 = *(const float4*)&cwave[192 + R + q * 4];
    cr[0] = (c0.x + c1.x) + (c2.x + c3.x);
    cr[1] = (c0.y + c1.y) + (c2.y + c3.y);
    cr[2] = (c0.z + c1.z) + (c2.z + c3.z);
    cr[3] = (c0.w + c1.w) + (c2.w + c3.w);
  }
  float bbv[5];
#pragma unroll
  for (int nt = 0; nt < 5; nt++) {
    int d = nt * 16 + li;
    bbv[nt] = (d < DIM) ? b2[d] : 0.f;
  }

  // ---- MFMA: h2pre[64][80] = adj @ g; wave w owns rows 16w..16w+15 ----
  short8 a0 = *(const short8*)&adjs[(R + li) * GPAD + q * 8];
  short8 a1 = *(const short8*)&adjs[(R + li) * GPAD + 32 + q * 8];
  floatx4 acc[5];
#pragma unroll
  for (int nt = 0; nt < 5; nt++) {
    floatx4 z = {0.f, 0.f, 0.f, 0.f};
    short8 b0 = *(const short8*)&gTs[(nt * 16 + li) * GPAD + q * 8];
    short8 b1 = *(const short8*)&gTs[(nt * 16 + li) * GPAD + 32 + q * 8];
    z = __builtin_amdgcn_mfma_f32_16x16x32_bf16(a0, b0, z, 0, 0, 0);
    z = __builtin_amdgcn_mfma_f32_16x16x32_bf16(a1, b1, z, 0, 0, 0);
    acc[nt] = z;
  }

  // ---- epilogue: y[d] = sum_m cvec[m] * relu(h2pre[m][d] + b2[d]) ----
#pragma unroll
  for (int nt = 0; nt < 5; nt++) {
    float bb = bbv[nt];
    float p = 0.f;
#pragma unroll
    for (int r = 0; r < 4; r++)
      p = fmaf(cr[r], fmaxf(acc[nt][r] + bb, 0.f), p);
    p += __shfl_xor(p, 16);
    p += __shfl_xor(p, 32);
    if (q == 0) yacc[w * 80 + nt * 16 + li] = p;
  }
  __syncthreads();   // barrier 2 of 2

  // ---- tail: wave 0 only; yv stage is wave-internal (no extra barrier) ----
  if (w == 0) {
    float* yv = cwave;                         // cwave dead after cr
    yv[lane] = yacc[lane] + yacc[80 + lane] + yacc[160 + lane] + yacc[240 + lane];
    if (lane < 16) {
      int d2 = 64 + lane;
      float v2s = 0.f;
      if (lane < 6)
        v2s = yacc[d2] + yacc[80 + d2] + yacc[160 + d2] + yacc[240 + d2];
      else if (lane < 13)
        v2s = sel[(size_t)b * 7 + (d2 - DIM)];
      yv[d2] = v2s;                            // 77..79 = 0
    }
    // projection: lane (qq, c): d = qq + 4j covers 0..79; yv[77..79]==0
    int c = lane & 15, qq = lane >> 4;
    float accp = 0.f;
    if (c < 11) {
#pragma unroll
      for (int j = 0; j < 20; j++) {
        int d = qq + 4 * j;
        int dd = (d < 77) ? d : 76;            // wp bounds; term is 0 anyway
        accp = fmaf(yv[d], wp[dd * 11 + c], accp);
      }
    }
    accp += __shfl_xor(accp, 16);
    accp += __shfl_xor(accp, 32);
    if (lane < 11) out[(size_t)b * 11 + lane] = accp + bp[lane];
  }
}

extern "C" void kernel_launch(void* const* d_in, const int* in_sizes, int n_in,
                              void* d_out, int out_size, void* d_ws, size_t ws_size,
                              hipStream_t stream) {
  const int*   atoms = (const int*)d_in[0];
  const float* adj   = (const float*)d_in[1];
  const float* sel   = (const float*)d_in[2];
  const float* emb   = (const float*)d_in[3];
  const float* w1    = (const float*)d_in[4];
  const float* b1    = (const float*)d_in[5];
  const float* w2    = (const float*)d_in[6];
  const float* b2    = (const float*)d_in[7];
  const float* wp    = (const float*)d_in[8];
  const float* bp    = (const float*)d_in[9];

  const int B = in_sizes[0] / NATOMS;          // 8192
  unsigned short* G = (unsigned short*)d_ws;   // 10000*72 bf16 = 1.44 MB

  precompute_G<<<(NFP + PGROWS - 1) / PGROWS, 256, 0, stream>>>(emb, w1, b1, w2, G);
  mol_fused<<<B, 256, 0, stream>>>(atoms, adj, sel, b2, wp, bp, G, (float*)d_out);
}